// Round 1
// baseline (115.613 us; speedup 1.0000x reference)
//
#include <hip/hip_runtime.h>

#define NPTS   262144
#define HID    20
#define NMID   8
#define NBLK   (NPTS / 256)

__device__ __forceinline__ float fast_tanh(float x) {
    // tanh(x) = 1 - 2/(exp(2x)+1); handles +/-inf saturation naturally.
    float e = __expf(2.0f * x);
    return 1.0f - __fdividef(2.0f, e + 1.0f);
}

__launch_bounds__(256, 2)
__global__ void pde_fused_kernel(const float* __restrict__ x,
                                 const float* __restrict__ W_in,
                                 const float* __restrict__ b_in,
                                 const float* __restrict__ W_mid,
                                 const float* __restrict__ b_mid,
                                 const float* __restrict__ W_out,
                                 const float* __restrict__ b_out,
                                 float* __restrict__ out) {
    // ---- stage all weights in LDS (~13.8 KB) ----
    __shared__ __align__(16) float sWm[NMID * HID * HID];   // 3200
    __shared__ float sbm[NMID * HID];                        // 160
    __shared__ float sWin[HID * 2];                          // 40
    __shared__ float sbin[HID];                              // 20
    __shared__ float sWout[HID];                             // 20
    __shared__ float sbout;

    const int tid = threadIdx.x;
    for (int t = tid; t < NMID * HID * HID; t += 256) sWm[t] = W_mid[t];
    if (tid < NMID * HID) sbm[tid] = b_mid[tid];
    if (tid < HID * 2)    sWin[tid] = W_in[tid];
    if (tid < HID)        sbin[tid] = b_in[tid];
    if (tid < HID)        sWout[tid] = W_out[tid];
    if (tid == 0)         sbout = b_out[0];
    __syncthreads();

    const int i = blockIdx.x * 256 + tid;

    const float2 xi = reinterpret_cast<const float2*>(x)[i];
    const float x0 = xi.x, x1 = xi.y;

    // state: value + three forward tangents (d/dt, d/dx, d2/dx2)
    float h[HID], ht[HID], hx[HID], hxx[HID];

    // ---- input layer: z = W_in @ x + b_in; z'' = 0 ----
    #pragma unroll
    for (int j = 0; j < HID; ++j) {
        const float w0 = sWin[j * 2 + 0];
        const float w1 = sWin[j * 2 + 1];
        const float z  = fmaf(w0, x0, fmaf(w1, x1, sbin[j]));
        const float a  = fast_tanh(z);
        const float s  = 1.0f - a * a;          // sech^2
        h[j]   = a;
        ht[j]  = s * w0;
        hx[j]  = s * w1;
        hxx[j] = -2.0f * a * s * w1 * w1;       // (1-a^2)*0 - 2a(1-a^2)(z')^2
    }

    // ---- 8 mid layers ----
    for (int layer = 0; layer < NMID; ++layer) {
        const float* Wl = &sWm[layer * HID * HID];
        const float* bl = &sbm[layer * HID];
        float hn[HID], hnt[HID], hnx[HID], hnxx[HID];
        #pragma unroll
        for (int j = 0; j < HID; ++j) {
            float z = bl[j], zt = 0.0f, zx = 0.0f, zxx = 0.0f;
            const float4* wr = reinterpret_cast<const float4*>(&Wl[j * HID]);
            #pragma unroll
            for (int k4 = 0; k4 < HID / 4; ++k4) {
                const float4 w = wr[k4];
                const int k = k4 * 4;
                z   = fmaf(w.x, h[k + 0],   z);
                zt  = fmaf(w.x, ht[k + 0],  zt);
                zx  = fmaf(w.x, hx[k + 0],  zx);
                zxx = fmaf(w.x, hxx[k + 0], zxx);
                z   = fmaf(w.y, h[k + 1],   z);
                zt  = fmaf(w.y, ht[k + 1],  zt);
                zx  = fmaf(w.y, hx[k + 1],  zx);
                zxx = fmaf(w.y, hxx[k + 1], zxx);
                z   = fmaf(w.z, h[k + 2],   z);
                zt  = fmaf(w.z, ht[k + 2],  zt);
                zx  = fmaf(w.z, hx[k + 2],  zx);
                zxx = fmaf(w.z, hxx[k + 2], zxx);
                z   = fmaf(w.w, h[k + 3],   z);
                zt  = fmaf(w.w, ht[k + 3],  zt);
                zx  = fmaf(w.w, hx[k + 3],  zx);
                zxx = fmaf(w.w, hxx[k + 3], zxx);
            }
            const float a = fast_tanh(z);
            const float s = 1.0f - a * a;
            hn[j]   = a;
            hnt[j]  = s * zt;
            hnx[j]  = s * zx;
            hnxx[j] = fmaf(s, zxx, -2.0f * a * s * zx * zx);
        }
        #pragma unroll
        for (int j = 0; j < HID; ++j) {
            h[j] = hn[j]; ht[j] = hnt[j]; hx[j] = hnx[j]; hxx[j] = hnxx[j];
        }
    }

    // ---- output layer (linear) ----
    float f = sbout, ft = 0.0f, fx = 0.0f, fxx = 0.0f;
    #pragma unroll
    for (int k = 0; k < HID; ++k) {
        const float w = sWout[k];
        f   = fmaf(w, h[k],   f);
        ft  = fmaf(w, ht[k],  ft);
        fx  = fmaf(w, hx[k],  fx);
        fxx = fmaf(w, hxx[k], fxx);
    }

    out[i] = f;

    // pde = B_F*x1^2 + f_t + 0.5*sigma^2*f_xx + B*x1*f_x - C^2/(4*C_F)*f_x^2
    const float pde = 0.5f * x1 * x1 + ft + 0.5f * fxx + 0.5f * x1 * fx
                      - 0.069444444444444f * fx * fx;
    out[NPTS + i] = pde;
}

extern "C" void kernel_launch(void* const* d_in, const int* in_sizes, int n_in,
                              void* d_out, int out_size, void* d_ws, size_t ws_size,
                              hipStream_t stream) {
    const float* x     = (const float*)d_in[0];
    const float* W_in  = (const float*)d_in[1];
    const float* b_in  = (const float*)d_in[2];
    const float* W_mid = (const float*)d_in[3];
    const float* b_mid = (const float*)d_in[4];
    const float* W_out = (const float*)d_in[5];
    const float* b_out = (const float*)d_in[6];
    float* out = (float*)d_out;

    hipLaunchKernelGGL(pde_fused_kernel, dim3(NBLK), dim3(256), 0, stream,
                       x, W_in, b_in, W_mid, b_mid, W_out, b_out, out);
}

// Round 3
// 81.742 us; speedup vs baseline: 1.4144x; 1.4144x over previous
//
#include <hip/hip_runtime.h>

#define NPTS 262144
#define HID  20
#define NMID 8

typedef float f32x16 __attribute__((ext_vector_type(16)));
typedef short short8 __attribute__((ext_vector_type(8)));
typedef unsigned int u32;

__device__ __forceinline__ u32 bf16_bits(float f) {
    u32 u = __builtin_bit_cast(u32, f);
    return (u + 0x7FFFu + ((u >> 16) & 1u)) >> 16;   // RNE, matches __float2bfloat16
}

__device__ __forceinline__ u32 pk_bf16(float lo, float hi) {
    return bf16_bits(lo) | (bf16_bits(hi) << 16);
}

__device__ __forceinline__ short8 mk_frag(const u32* d, int o) {
    uint4 v = make_uint4(d[o + 0], d[o + 1], d[o + 2], d[o + 3]);
    return __builtin_bit_cast(short8, v);
}

// C/D (32x32): value(row n, col p) at lane = p + 32*((n>>2)&1), reg = (n&3) + 4*(n>>3).
// B (32x32x16, K-step s): element k = 16s + 8*(lane>>5) + r at lane = p + 32*((k>>3)&1).
// => B[s][r] for dest-half hi = cvtpk(val[(r&3)+8s+4*hi], val[...+1]) sourced from half (r>>2)&1.
__device__ __forceinline__ void relayout(const float* v, int hi, u32* outd) {
    #pragma unroll
    for (int s = 0; s < 2; ++s) {
        u32 C0 = pk_bf16(v[8 * s + 0], v[8 * s + 1]);
        u32 C1 = pk_bf16(v[8 * s + 2], v[8 * s + 3]);
        u32 C2 = pk_bf16(v[8 * s + 4], v[8 * s + 5]);
        u32 C3 = pk_bf16(v[8 * s + 6], v[8 * s + 7]);
        u32 C0x = (u32)__shfl_xor((int)C0, 32);
        u32 C1x = (u32)__shfl_xor((int)C1, 32);
        u32 C2x = (u32)__shfl_xor((int)C2, 32);
        u32 C3x = (u32)__shfl_xor((int)C3, 32);
        outd[4 * s + 0] = hi ? C2x : C0;   // r=0,1
        outd[4 * s + 1] = hi ? C3x : C1;   // r=2,3
        outd[4 * s + 2] = hi ? C2  : C0x;  // r=4,5
        outd[4 * s + 3] = hi ? C3  : C1x;  // r=6,7
    }
}

__launch_bounds__(256, 2)
__global__ void pde_mfma_kernel(const float* __restrict__ x,
                                const float* __restrict__ W_in,
                                const float* __restrict__ b_in,
                                const float* __restrict__ W_mid,
                                const float* __restrict__ b_mid,
                                const float* __restrict__ W_out,
                                const float* __restrict__ b_out,
                                float* __restrict__ out) {
    // A-fragments of padded weights (bias folded in as column k=20), bf16:
    // sWf[((layer*2+s)*64 + lane)*8 + r] = Wp[j = lane&31][k = 16s + 8*(lane>>5) + r]
    __shared__ short sWf[NMID * 2 * 64 * 8];       // 16 KB
    __shared__ float sIn[2 * 16 * 4];              // (w_in0, w_in1, b_in, w_out)[hi][reg]

    const int tid = threadIdx.x;

    for (int idx = tid; idx < NMID * 2 * 64 * 8 / 2; idx += 256)
        ((u32*)sWf)[idx] = 0u;
    for (int idx = tid; idx < 32; idx += 256) {
        int h2 = idx >> 4, reg = idx & 15;
        int n = (reg & 3) + 8 * (reg >> 2) + 4 * h2;
        float w0 = 0.f, w1 = 0.f, b = 0.f, wo = 0.f;
        if (n < HID) { w0 = W_in[n * 2]; w1 = W_in[n * 2 + 1]; b = b_in[n]; wo = W_out[n]; }
        sIn[idx * 4 + 0] = w0; sIn[idx * 4 + 1] = w1;
        sIn[idx * 4 + 2] = b;  sIn[idx * 4 + 3] = wo;
    }
    __syncthreads();
    for (int idx = tid; idx < NMID * HID * (HID + 1); idx += 256) {
        int layer = idx / (HID * (HID + 1));
        int rem   = idx % (HID * (HID + 1));
        int j = rem / (HID + 1);
        int k = rem % (HID + 1);
        float w = (k < HID) ? W_mid[(layer * HID + j) * HID + k] : b_mid[layer * HID + j];
        int s = k >> 4, kk = k & 15, h2 = kk >> 3, r = kk & 7;
        int lane = j + 32 * h2;
        sWf[((layer * 2 + s) * 64 + lane) * 8 + r] = (short)bf16_bits(w);
    }
    __syncthreads();

    const int lane = tid & 63;
    const int wv   = tid >> 6;
    const int p    = lane & 31;
    const int hi   = lane >> 5;
    const int P    = blockIdx.x * 128 + wv * 32 + p;

    const float2 xv = reinterpret_cast<const float2*>(x)[P];
    const float x0 = xv.x, x1 = xv.y;
    const float bo = b_out[0];

    const float4* sIn4 = reinterpret_cast<const float4*>(sIn);

    float vh[16], vt[16], vx[16], vxx[16];

    // ---- input layer (fp32 VALU, directly in C/D-val layout) ----
    #pragma unroll
    for (int r = 0; r < 16; ++r) {
        float4 t = sIn4[hi * 16 + r];
        float z = fmaf(t.x, x0, fmaf(t.y, x1, t.z));
        float e = __expf(2.0f * z);
        float a = 1.0f - __fdividef(2.0f, e + 1.0f);
        float s = 1.0f - a * a;
        float sx = s * t.y;
        vh[r] = a; vt[r] = s * t.x; vx[r] = sx;
        vxx[r] = -2.0f * a * sx * t.y;
    }

    const f32x16 zz = 0.0f;
    const u32 keep = hi ? 0xFFFFFFFFu : 0xFFFF0000u;
    const u32 ins  = hi ? 0u : 0x00003F80u;   // bf16 1.0 into B element k=20 (h stream)

    // ---- 8 mid layers on MFMA ----
    for (int layer = 0; layer < NMID; ++layer) {
        u32 dh[8], dt[8], dx[8], dxx[8];
        relayout(vh,  hi, dh);
        relayout(vt,  hi, dt);
        relayout(vx,  hi, dx);
        relayout(vxx, hi, dxx);
        dh[6] = (dh[6] & keep) | ins;   // bias column input = 1.0

        const short8* af = reinterpret_cast<const short8*>(&sWf[(layer * 2) * 64 * 8]);
        short8 a0 = af[lane];
        short8 a1 = af[64 + lane];

        f32x16 aH  = __builtin_amdgcn_mfma_f32_32x32x16_bf16(a0, mk_frag(dh, 0), zz, 0, 0, 0);
        aH         = __builtin_amdgcn_mfma_f32_32x32x16_bf16(a1, mk_frag(dh, 4), aH, 0, 0, 0);
        f32x16 aT  = __builtin_amdgcn_mfma_f32_32x32x16_bf16(a0, mk_frag(dt, 0), zz, 0, 0, 0);
        aT         = __builtin_amdgcn_mfma_f32_32x32x16_bf16(a1, mk_frag(dt, 4), aT, 0, 0, 0);
        f32x16 aX  = __builtin_amdgcn_mfma_f32_32x32x16_bf16(a0, mk_frag(dx, 0), zz, 0, 0, 0);
        aX         = __builtin_amdgcn_mfma_f32_32x32x16_bf16(a1, mk_frag(dx, 4), aX, 0, 0, 0);
        f32x16 aXX = __builtin_amdgcn_mfma_f32_32x32x16_bf16(a0, mk_frag(dxx, 0), zz, 0, 0, 0);
        aXX        = __builtin_amdgcn_mfma_f32_32x32x16_bf16(a1, mk_frag(dxx, 4), aXX, 0, 0, 0);

        #pragma unroll
        for (int r = 0; r < 16; ++r) {
            float z   = aH[r];                   // includes bias via k=20 column
            float e   = __expf(2.0f * z);
            float a   = 1.0f - __fdividef(2.0f, e + 1.0f);
            float s   = 1.0f - a * a;
            float zt  = aT[r], zx = aX[r], zxx = aXX[r];
            float sx  = s * zx;
            vh[r] = a; vt[r] = s * zt; vx[r] = sx;
            vxx[r] = fmaf(s, zxx, -2.0f * a * sx * zx);
        }
    }

    // ---- output layer ----
    float f = 0.f, ft = 0.f, fx = 0.f, fxx = 0.f;
    #pragma unroll
    for (int r = 0; r < 16; ++r) {
        float4 t = sIn4[hi * 16 + r];
        f   = fmaf(t.w, vh[r],  f);
        ft  = fmaf(t.w, vt[r],  ft);
        fx  = fmaf(t.w, vx[r],  fx);
        fxx = fmaf(t.w, vxx[r], fxx);
    }
    f   += __shfl_xor(f, 32);
    ft  += __shfl_xor(ft, 32);
    fx  += __shfl_xor(fx, 32);
    fxx += __shfl_xor(fxx, 32);
    f += bo;

    if (!hi) {
        const float pde = 0.5f * x1 * x1 + ft + 0.5f * fxx + 0.5f * x1 * fx
                          - 0.069444444444444f * fx * fx;
        out[P] = f;
        out[NPTS + P] = pde;
    }
}

extern "C" void kernel_launch(void* const* d_in, const int* in_sizes, int n_in,
                              void* d_out, int out_size, void* d_ws, size_t ws_size,
                              hipStream_t stream) {
    const float* x     = (const float*)d_in[0];
    const float* W_in  = (const float*)d_in[1];
    const float* b_in  = (const float*)d_in[2];
    const float* W_mid = (const float*)d_in[3];
    const float* b_mid = (const float*)d_in[4];
    const float* W_out = (const float*)d_in[5];
    const float* b_out = (const float*)d_in[6];
    float* out = (float*)d_out;

    hipLaunchKernelGGL(pde_mfma_kernel, dim3(NPTS / 128), dim3(256), 0, stream,
                       x, W_in, b_in, W_mid, b_mid, W_out, b_out, out);
}